// Round 3
// baseline (473.571 us; speedup 1.0000x reference)
//
#include <hip/hip_runtime.h>

// ---------------------------------------------------------------------------
// GCN block: 3x (MFMA bf16 GEMM -> degree-normalized aggregate), resid, relu.
// 10 dispatches: memset(deg) | deg-count | scan(+pad,+dinv,+rp2,+cur) | fill |
//   gemm1 | agg1 | gemm2 | agg2 | gemm3 | agg3
// R15 change: bucket scatter+sort pipeline REPLACED by per-node direct CSR
// build. R14 post-mortem: scatter time was invariant to block count (47us at
// 6.9% AND 23% occupancy) => serialized on 512-address global cursor atomics
// (782/address) + LDS histogram atomics (368K conflict cycles), and packed[]
// round-trip wrote 29MB piecemeal. New structure: deg atomics spread over
// 100K addresses (~16/addr), per-bucket LDS scan into disjoint CAPCOL
// regions (still no global scan), direct col fill (~16/addr atomics).
// Deletes packed[] entirely.
// R14: agg col loads direct (no shfl in chain), x4 padding. R13: 1 node/wave,
// 4 features/lane, 4 edges/load. R10 lesson: no barrier-coupled gather
// fusion. R9: dinv folded into GEMM epilogue.
// ---------------------------------------------------------------------------

#define LB 8
#define BKN 256
#define CAP 8192                   // edge slots per bucket (mean fill 4096)
#define PADS 3                     // segment padding to x4
#define CAPCOL (CAP + BKN * PADS)  // padded col region per bucket of 256 nodes

typedef unsigned short ushort_t;
typedef __attribute__((ext_vector_type(8))) short bf16x8;
typedef __attribute__((ext_vector_type(4))) float f32x4;

__device__ __forceinline__ unsigned f2bf(float f) {
    unsigned u = __builtin_bit_cast(unsigned, f);
    return (u + 0x7FFFu + ((u >> 16) & 1u)) >> 16;   // RNE
}
__device__ __forceinline__ float bf2f(ushort_t h) {
    unsigned u = ((unsigned)h) << 16;
    return __builtin_bit_cast(float, u);
}
__device__ __forceinline__ float bflo(unsigned u) {
    return __builtin_bit_cast(float, u << 16);
}
__device__ __forceinline__ float bfhi(unsigned u) {
    return __builtin_bit_cast(float, u & 0xFFFF0000u);
}

// per-block int64-vs-int32 probe (sampled; same result in every block).
// 512 dwords = 256 sampled high-words; P(false int64 | int32 ids) ~ 0.
__device__ int detect_f64(const int* ei, int E, int* sflag) {
    if (threadIdx.x == 0) *sflag = 0;
    __syncthreads();
    const unsigned* raw = (const unsigned*)ei;
    int dwords = min(2 * E, 512);
    int any = 0;
    for (int i = threadIdx.x; i < dwords; i += blockDim.x)
        if ((i & 1) && raw[i]) any = 1;
    if (any) atomicOr(sflag, 1);
    __syncthreads();
    return !*sflag;   // all sampled high words zero => int64
}

// ---- pass 1: in-degree count, atomics spread over N addresses -------------
__global__ __launch_bounds__(256) void k_deg(
        const int* __restrict__ ei, int E, int* __restrict__ deg) {
    __shared__ int sflag;
    int f64 = detect_f64(ei, E, &sflag);
    int stride = gridDim.x * 256;
    for (int e = blockIdx.x * 256 + threadIdx.x; e < E; e += stride) {
        int d = f64 ? ei[2 * (E + e)] : ei[E + e];
        atomicAdd(&deg[d], 1);
    }
}

// ---- pass 2: per-bucket scan of padded degrees -> rp2, dinv, cur, pad -----
// Bucket b = nodes [b*256, b*256+256) gets disjoint col region b*CAPCOL.
__global__ __launch_bounds__(256) void k_scan(
        const int* __restrict__ deg, int* __restrict__ cur, int* __restrict__ col,
        int2* __restrict__ rp2, float* __restrict__ dinv,
        ushort_t* __restrict__ hs, int N) {
    __shared__ int s[BKN];
    int tid = threadIdx.x;
    int b = blockIdx.x;
    int node = (b << LB) + tid;
    int v = (node < N) ? deg[node] : 0;
    int pv = (v + PADS) & ~PADS;        // padded length (x4)
    s[tid] = pv;
    __syncthreads();
    for (int off = 1; off < 256; off <<= 1) {
        int x = (tid >= off) ? s[tid - off] : 0;
        __syncthreads();
        if (tid >= off) s[tid] += x;
        __syncthreads();
    }
    int st = b * CAPCOL + s[tid] - pv;  // exclusive prefix within bucket
    if (node < N) {
        rp2[node] = make_int2(st, st + pv);
        dinv[node] = rsqrtf((float)(v + 1));   // +1 self loop
        cur[node] = st;
        for (int i = v; i < pv; i++) col[st + i] = N;   // sentinel padding
    }
    if (b == 0 && tid < 64) hs[(size_t)N * 64 + tid] = 0;   // zero row N
}

// ---- pass 3: direct CSR fill, atomics spread over N addresses -------------
__global__ __launch_bounds__(256) void k_fill(
        const int* __restrict__ ei, int E,
        int* __restrict__ cur, int* __restrict__ col) {
    __shared__ int sflag;
    int f64 = detect_f64(ei, E, &sflag);
    int stride = gridDim.x * 256;
    for (int e = blockIdx.x * 256 + threadIdx.x; e < E; e += stride) {
        int d = f64 ? ei[2 * (E + e)] : ei[E + e];
        int s = f64 ? ei[2 * e] : ei[e];
        int pos = atomicAdd(&cur[d], 1);
        col[pos] = s;
    }
}

// ---- gemm1: (N x 128) @ (128 x 64), f32 in, dinv-scaled, bf16 out ---------
__global__ __launch_bounds__(256) void k_gemm1(
        const float* __restrict__ A, const float* __restrict__ W,
        const float* __restrict__ dinv, ushort_t* __restrict__ out, int nrows) {
    const int K = 128;
    __shared__ ushort_t sWT[64 * (K + 8)];
    int tid = threadIdx.x;
    for (int i = tid; i < K * 64; i += 256) {
        int n = i & 63, k = i >> 6;
        sWT[n * (K + 8) + k] = (ushort_t)f2bf(W[i]);
    }
    __syncthreads();
    int wave = tid >> 6, lane = tid & 63;
    int quad = lane >> 4, l16 = lane & 15;
    int rowBase = blockIdx.x * 128 + wave * 32;
    f32x4 acc[2][4];
#pragma unroll
    for (int r = 0; r < 2; r++)
#pragma unroll
        for (int c = 0; c < 4; c++) acc[r][c] = (f32x4){0.f, 0.f, 0.f, 0.f};
#pragma unroll
    for (int chunk = 0; chunk < K / 32; chunk++) {
        bf16x8 afr[2];
#pragma unroll
        for (int r = 0; r < 2; r++) {
            int row = rowBase + r * 16 + l16;
            if (row >= nrows) row = nrows - 1;
            const float* ap = A + (size_t)row * K + chunk * 32 + quad * 8;
            float4 v0 = *(const float4*)ap;
            float4 v1 = *(const float4*)(ap + 4);
            bf16x8 a;
            a[0] = (short)f2bf(v0.x); a[1] = (short)f2bf(v0.y);
            a[2] = (short)f2bf(v0.z); a[3] = (short)f2bf(v0.w);
            a[4] = (short)f2bf(v1.x); a[5] = (short)f2bf(v1.y);
            a[6] = (short)f2bf(v1.z); a[7] = (short)f2bf(v1.w);
            afr[r] = a;
        }
#pragma unroll
        for (int c = 0; c < 4; c++) {
            bf16x8 bfr = __builtin_bit_cast(
                bf16x8,
                *(const uint4*)&sWT[(c * 16 + l16) * (K + 8) + chunk * 32 + quad * 8]);
#pragma unroll
            for (int r = 0; r < 2; r++)
                acc[r][c] = __builtin_amdgcn_mfma_f32_16x16x32_bf16(
                    afr[r], bfr, acc[r][c], 0, 0, 0);
        }
    }
#pragma unroll
    for (int r = 0; r < 2; r++)
#pragma unroll
        for (int i = 0; i < 4; i++) {
            int row = rowBase + r * 16 + quad * 4 + i;
            if (row < nrows) {
                float sc = dinv[row];
#pragma unroll
                for (int c = 0; c < 4; c++)
                    out[(size_t)row * 64 + c * 16 + l16] =
                        (ushort_t)f2bf(acc[r][c][i] * sc);
            }
        }
}

// ---- gemm64: (N x 64) @ (64 x 64), bf16 in, dinv-scaled, bf16 out ---------
__global__ __launch_bounds__(256) void k_gemm64(
        const ushort_t* __restrict__ A, const float* __restrict__ W,
        const float* __restrict__ dinv, ushort_t* __restrict__ out, int nrows) {
    const int K = 64;
    __shared__ ushort_t sWT[64 * (K + 8)];
    int tid = threadIdx.x;
    for (int i = tid; i < K * 64; i += 256) {
        int n = i & 63, k = i >> 6;
        sWT[n * (K + 8) + k] = (ushort_t)f2bf(W[i]);
    }
    __syncthreads();
    int wave = tid >> 6, lane = tid & 63;
    int quad = lane >> 4, l16 = lane & 15;
    int rowBase = blockIdx.x * 128 + wave * 32;
    f32x4 acc[2][4];
#pragma unroll
    for (int r = 0; r < 2; r++)
#pragma unroll
        for (int c = 0; c < 4; c++) acc[r][c] = (f32x4){0.f, 0.f, 0.f, 0.f};
#pragma unroll
    for (int chunk = 0; chunk < K / 32; chunk++) {
        bf16x8 afr[2];
#pragma unroll
        for (int r = 0; r < 2; r++) {
            int row = rowBase + r * 16 + l16;
            if (row >= nrows) row = nrows - 1;
            const ushort_t* ap = A + (size_t)row * K + chunk * 32 + quad * 8;
            afr[r] = __builtin_bit_cast(bf16x8, *(const uint4*)ap);
        }
#pragma unroll
        for (int c = 0; c < 4; c++) {
            bf16x8 bfr = __builtin_bit_cast(
                bf16x8,
                *(const uint4*)&sWT[(c * 16 + l16) * (K + 8) + chunk * 32 + quad * 8]);
#pragma unroll
            for (int r = 0; r < 2; r++)
                acc[r][c] = __builtin_amdgcn_mfma_f32_16x16x32_bf16(
                    afr[r], bfr, acc[r][c], 0, 0, 0);
        }
    }
#pragma unroll
    for (int r = 0; r < 2; r++)
#pragma unroll
        for (int i = 0; i < 4; i++) {
            int row = rowBase + r * 16 + quad * 4 + i;
            if (row < nrows) {
                float sc = dinv[row];
#pragma unroll
                for (int c = 0; c < 4; c++)
                    out[(size_t)row * 64 + c * 16 + l16] =
                        (ushort_t)f2bf(acc[r][c][i] * sc);
            }
        }
}

// ---- aggregation: ONE node per wave, 4 features/lane, 4 edges/load --------
// Row = 64 bf16 = 128B = 16 lanes x uint2. Lane group g = lane>>4 handles
// edge slot 4t+g of load t; col[e+4t+g] loaded DIRECTLY (16 lanes broadcast-
// share the address; a burst's 4 col loads cover one 64B line) -- no shfl in
// the dependency chain, vmcnt-only waits. Segments padded to x4 (sentinel row
// N = zeros). Main loop: 4 unconditional loads (16 edges); tails: 8 then 4.
// Cross-group reduce via shfl_xor(16/32); lanes 0-15 write the row.
template <int RELU, int F32OUT>
__global__ __launch_bounds__(256) void k_agg4e(
        const ushort_t* __restrict__ hs, const float* __restrict__ dinv,
        const float* __restrict__ bias, const int* __restrict__ col,
        const int2* __restrict__ rp2, const ushort_t* __restrict__ residb,
        float* __restrict__ outf, ushort_t* __restrict__ outb, int n) {
    int node = (int)((blockIdx.x * blockDim.x + threadIdx.x) >> 6);
    if (node >= n) return;
    int lane = threadIdx.x & 63;
    int g = lane >> 4;                   // edge sub-slot within a burst
    int c4 = lane & 15;                  // feature group: cols c4*4..c4*4+3
    const ushort_t* hrow = hs + (size_t)c4 * 4;
    int2 r = rp2[node];
    int e = r.x, p = r.y;                // p-e multiple of 4
    uint2 us = *(const uint2*)(hs + (size_t)node * 64 + c4 * 4);  // self loop
    float a0 = 0.f, a1 = 0.f, a2 = 0.f, a3 = 0.f;

#define GR(m) (*(const uint2*)(hrow + (size_t)(m) * 64))
#define GACC(u)                                                             \
    a0 += bflo(u.x); a1 += bfhi(u.x);                                       \
    a2 += bflo(u.y); a3 += bfhi(u.y);

    for (; e + 16 <= p; e += 16) {
        int m0 = col[e + g];
        int m1 = col[e + 4 + g];
        int m2 = col[e + 8 + g];
        int m3 = col[e + 12 + g];
        uint2 u0 = GR(m0);
        uint2 u1 = GR(m1);
        uint2 u2 = GR(m2);
        uint2 u3 = GR(m3);
        GACC(u0) GACC(u1) GACC(u2) GACC(u3)
    }
    if (p - e >= 8) {
        int m0 = col[e + g];
        int m1 = col[e + 4 + g];
        uint2 u0 = GR(m0);
        uint2 u1 = GR(m1);
        GACC(u0) GACC(u1)
        e += 8;
    }
    if (e < p) {                         // exactly 4 edges remain
        int m0 = col[e + g];
        uint2 u0 = GR(m0);
        GACC(u0)
    }
#undef GR
#undef GACC

    a0 += __shfl_xor(a0, 16); a0 += __shfl_xor(a0, 32);
    a1 += __shfl_xor(a1, 16); a1 += __shfl_xor(a1, 32);
    a2 += __shfl_xor(a2, 16); a2 += __shfl_xor(a2, 32);
    a3 += __shfl_xor(a3, 16); a3 += __shfl_xor(a3, 32);

    if (lane < 16) {
        a0 += bflo(us.x); a1 += bfhi(us.x);
        a2 += bflo(us.y); a3 += bfhi(us.y);
        float sc = dinv[node];
        float4 bv = *(const float4*)(bias + c4 * 4);
        float o0 = sc * a0 + bv.x, o1 = sc * a1 + bv.y;
        float o2 = sc * a2 + bv.z, o3 = sc * a3 + bv.w;
        if (RELU) {
            o0 = fmaxf(o0, 0.f); o1 = fmaxf(o1, 0.f);
            o2 = fmaxf(o2, 0.f); o3 = fmaxf(o3, 0.f);
        }
        if (F32OUT) {
            uint2 rb = *(const uint2*)(residb + (size_t)node * 64 + c4 * 4);
            o0 += bflo(rb.x); o1 += bfhi(rb.x);
            o2 += bflo(rb.y); o3 += bfhi(rb.y);
            *(float4*)(outf + (size_t)node * 64 + c4 * 4) =
                make_float4(o0, o1, o2, o3);
        } else {
            unsigned w0 = f2bf(o0) | (f2bf(o1) << 16);
            unsigned w1 = f2bf(o2) | (f2bf(o3) << 16);
            *(uint2*)(outb + (size_t)node * 64 + c4 * 4) = make_uint2(w0, w1);
        }
    }
}

// ---------------------------------------------------------------------------
extern "C" void kernel_launch(void* const* d_in, const int* in_sizes, int n_in,
                              void* d_out, int out_size, void* d_ws, size_t ws_size,
                              hipStream_t stream) {
    const float* x  = (const float*)d_in[0];
    const int*   ei = (const int*)d_in[1];
    const float* W0 = (const float*)d_in[2];
    const float* b0 = (const float*)d_in[3];
    const float* Ws = (const float*)d_in[4];
    const float* bs = (const float*)d_in[5];
    float* out = (float*)d_out;

    const int N = in_sizes[0] / 128;
    const int E = in_sizes[1] / 2;
    const int B = (N + BKN - 1) >> LB;

    char* p = (char*)d_ws;
    auto carve = [&](size_t bytes) {
        char* r = p;
        p += (bytes + 255) & ~(size_t)255;
        return r;
    };
    int*      deg  = (int*)carve((size_t)N * 4);
    int*      cur  = (int*)carve((size_t)N * 4);
    int*      col  = (int*)carve(((size_t)B * CAPCOL + 64) * 4);
    int2*     rp2  = (int2*)carve((size_t)N * 8);
    float*    dinv = (float*)carve((size_t)N * 4);
    ushort_t* hs   = (ushort_t*)carve((size_t)(N + 1) * 64 * 2); // +sentinel row
    ushort_t* xtb  = (ushort_t*)carve((size_t)N * 64 * 2);
    ushort_t* hb   = (ushort_t*)carve((size_t)N * 64 * 2);

    hipMemsetAsync(deg, 0, (size_t)N * 4, stream);

    int eb = min((E + 255) / 256, 2048);   // grid-stride blocks for edge passes
    k_deg<<<eb, 256, 0, stream>>>(ei, E, deg);
    k_scan<<<B, 256, 0, stream>>>(deg, cur, col, rp2, dinv, hs, N);
    k_fill<<<eb, 256, 0, stream>>>(ei, E, cur, col);

    int gb = (N + 127) / 128;
    int ablocks = (N + 3) / 4;   // 1 node/wave, 4 waves/block

    // layer 1: hs = (x @ W0) * dinv ; agg1 -> xtb (bf16, +b0, no relu)
    k_gemm1<<<gb, 256, 0, stream>>>(x, W0, dinv, hs, N);
    k_agg4e<0, 0><<<ablocks, 256, 0, stream>>>(hs, dinv, b0, col, rp2,
                                               nullptr, nullptr, xtb, N);
    // layer 2: hs = (xtb @ Ws0) * dinv ; agg2 -> hb (bf16, +bs0, relu)
    k_gemm64<<<gb, 256, 0, stream>>>(xtb, Ws, dinv, hs, N);
    k_agg4e<1, 0><<<ablocks, 256, 0, stream>>>(hs, dinv, bs, col, rp2,
                                               nullptr, nullptr, hb, N);
    // layer 3: hs = (hb @ Ws1) * dinv ; agg3 -> out (f32, +bs1, relu, +resid)
    k_gemm64<<<gb, 256, 0, stream>>>(hb, Ws + 64 * 64, dinv, hs, N);
    k_agg4e<1, 1><<<ablocks, 256, 0, stream>>>(hs, dinv, bs + 64, col, rp2,
                                               xtb, out, nullptr, N);
}

// Round 4
// 294.250 us; speedup vs baseline: 1.6094x; 1.6094x over previous
//
#include <hip/hip_runtime.h>

// ---------------------------------------------------------------------------
// GCN block: 3x (MFMA bf16 GEMM -> degree-normalized aggregate), resid, relu.
// 9 dispatches: memset(cursors) | scatter(fixed-CAP buckets) |
//   sort(+pad,+dinv,+rp2) | gemm1 | agg1 | gemm2 | agg2 | gemm3 | agg3
// R16: REVERT to bucket scatter+sort (R15 post-mortem: direct CSR fill dies
// on write amplification -- 104MB of full-line writebacks from random 4B col
// writes, 148us; bucketed sort writes col within a 36KB L2-local region).
// Two latency fixes on top of the R13/R14 structure:
//  * k_scatter reads ei ONCE (16 edges/thread in unrolled regs, CHUNK 4096);
//    hist + fill passes run from regs. One fewer 25.6MB global pass + chain.
//  * k_agg4e software-pipelines col loads depth-2: next burst's col loads
//    issue BEFORE accumulating current gathers, removing col latency from
//    the per-burst critical chain (gathers wait vmcnt(4), cols ride behind).
// R14: direct col loads (no shfl in chain), x4 padding. R13: 1 node/wave,
// 4 features/lane, 4 edges/load. R10 lesson: no barrier-coupled gather
// fusion. R9: dinv folded into GEMM epilogue.
// ---------------------------------------------------------------------------

#define LB 8
#define BKN 256
#define CHUNK 4096
#define EPT 16                     // edges per thread in scatter (CHUNK/256)
#define CAP 8192                   // packed slots per bucket (mean fill 4092)
#define PADS 3                     // segment padding to x4
#define CAPCOL (CAP + BKN * PADS)  // padded col region per bucket

typedef unsigned short ushort_t;
typedef __attribute__((ext_vector_type(8))) short bf16x8;
typedef __attribute__((ext_vector_type(4))) float f32x4;

__device__ __forceinline__ unsigned f2bf(float f) {
    unsigned u = __builtin_bit_cast(unsigned, f);
    return (u + 0x7FFFu + ((u >> 16) & 1u)) >> 16;   // RNE
}
__device__ __forceinline__ float bf2f(ushort_t h) {
    unsigned u = ((unsigned)h) << 16;
    return __builtin_bit_cast(float, u);
}
__device__ __forceinline__ float bflo(unsigned u) {
    return __builtin_bit_cast(float, u << 16);
}
__device__ __forceinline__ float bfhi(unsigned u) {
    return __builtin_bit_cast(float, u & 0xFFFF0000u);
}

// per-block int64-vs-int32 probe (sampled; same result in every block)
__device__ int detect_f64(const int* ei, int E, int* sflag) {
    if (threadIdx.x == 0) *sflag = 0;
    __syncthreads();
    const unsigned* raw = (const unsigned*)ei;
    int dwords = min(2 * E, 512);
    int any = 0;
    for (int i = threadIdx.x; i < dwords; i += blockDim.x)
        if ((i & 1) && raw[i]) any = 1;
    if (any) atomicOr(sflag, 1);
    __syncthreads();
    return !*sflag;   // all sampled high words zero => int64
}

// ---- scatter: partition edges into fixed-CAP bucket regions ---------------
// packed[b*CAP + cursor] = (src<<8 | dst&255); cursor is RELATIVE (0-init).
// Single pass over ei: each thread keeps its EPT edges in (unrolled) regs.
__global__ __launch_bounds__(256) void k_scatter(
        const int* __restrict__ ei, int E,
        int* __restrict__ bucketCursor, unsigned int* __restrict__ packed) {
    __shared__ int hist[512];
    __shared__ int base[512];
    __shared__ int sflag;
    int f64 = detect_f64(ei, E, &sflag);
    int b0 = blockIdx.x * CHUNK;
    int n = min(CHUNK, E - b0);
    int tid = threadIdx.x;
    for (int i = tid; i < 512; i += 256) hist[i] = 0;
    __syncthreads();
    int dreg[EPT], sreg[EPT];
#pragma unroll
    for (int i = 0; i < EPT; i++) {
        int idx = tid + i * 256;
        if (idx < n) {
            int e = b0 + idx;
            dreg[i] = f64 ? ei[2 * (E + e)] : ei[E + e];
            sreg[i] = f64 ? ei[2 * e] : ei[e];
            atomicAdd(&hist[dreg[i] >> LB], 1);
        }
    }
    __syncthreads();
    for (int i = tid; i < 512; i += 256) {
        int c = hist[i];
        base[i] = c ? atomicAdd(&bucketCursor[i], c) : 0;
        hist[i] = 0;
    }
    __syncthreads();
#pragma unroll
    for (int i = 0; i < EPT; i++) {
        int idx = tid + i * 256;
        if (idx < n) {
            int bk = dreg[i] >> LB;
            int pos = bk * CAP + base[bk] + atomicAdd(&hist[bk], 1);
            packed[pos] = ((unsigned)sreg[i] << LB) | (unsigned)(dreg[i] & (BKN - 1));
        }
    }
}

// ---- per-bucket counting sort -> padded CSR col[], rp2, dinv --------------
// Bucket b's packed region: [b*CAP, b*CAP + cnt) with cnt = bucketCursor[b].
// Node segments padded to x4 with sentinel index N; hs row N zeroed here.
// col scatter-writes land within this bucket's 36KB CAPCOL region (L2-local).
__global__ __launch_bounds__(256) void k_sort(
        const unsigned int* __restrict__ packed, const int* __restrict__ bucketCursor,
        int* __restrict__ col, int2* __restrict__ rp2, float* __restrict__ dinv,
        ushort_t* __restrict__ hs, int N) {
    __shared__ int hist[BKN];
    __shared__ int s[BKN];
    __shared__ int cur[BKN];
    int tid = threadIdx.x;
    int b = blockIdx.x;
    int start = b * CAP;
    int end = start + bucketCursor[b];
    hist[tid] = 0;
    __syncthreads();
    for (int e = start + tid; e < end; e += 256)
        atomicAdd(&hist[packed[e] & (BKN - 1)], 1);
    __syncthreads();
    int v = hist[tid];
    int pv = (v + PADS) & ~PADS;        // padded length (x4)
    s[tid] = pv;
    __syncthreads();
    for (int off = 1; off < 256; off <<= 1) {
        int x = (tid >= off) ? s[tid - off] : 0;
        __syncthreads();
        if (tid >= off) s[tid] += x;
        __syncthreads();
    }
    int excl = s[tid] - pv;
    int st = b * CAPCOL + excl;         // padded col base, buckets disjoint
    cur[tid] = st;
    int node = (b << LB) + tid;
    if (node < N) {
        rp2[node] = make_int2(st, st + pv);
        dinv[node] = rsqrtf((float)(v + 1));   // +1 self loop
        for (int i = v; i < pv; i++) col[st + i] = N;   // sentinel padding
    }
    if (b == 0 && tid < 64) hs[(size_t)N * 64 + tid] = 0;   // zero row N
    __syncthreads();
    for (int e = start + tid; e < end; e += 256) {
        unsigned pvk = packed[e];
        int pos = atomicAdd(&cur[pvk & (BKN - 1)], 1);
        col[pos] = (int)(pvk >> LB);
    }
}

// ---- gemm1: (N x 128) @ (128 x 64), f32 in, dinv-scaled, bf16 out ---------
__global__ __launch_bounds__(256) void k_gemm1(
        const float* __restrict__ A, const float* __restrict__ W,
        const float* __restrict__ dinv, ushort_t* __restrict__ out, int nrows) {
    const int K = 128;
    __shared__ ushort_t sWT[64 * (K + 8)];
    int tid = threadIdx.x;
    for (int i = tid; i < K * 64; i += 256) {
        int n = i & 63, k = i >> 6;
        sWT[n * (K + 8) + k] = (ushort_t)f2bf(W[i]);
    }
    __syncthreads();
    int wave = tid >> 6, lane = tid & 63;
    int quad = lane >> 4, l16 = lane & 15;
    int rowBase = blockIdx.x * 128 + wave * 32;
    f32x4 acc[2][4];
#pragma unroll
    for (int r = 0; r < 2; r++)
#pragma unroll
        for (int c = 0; c < 4; c++) acc[r][c] = (f32x4){0.f, 0.f, 0.f, 0.f};
#pragma unroll
    for (int chunk = 0; chunk < K / 32; chunk++) {
        bf16x8 afr[2];
#pragma unroll
        for (int r = 0; r < 2; r++) {
            int row = rowBase + r * 16 + l16;
            if (row >= nrows) row = nrows - 1;
            const float* ap = A + (size_t)row * K + chunk * 32 + quad * 8;
            float4 v0 = *(const float4*)ap;
            float4 v1 = *(const float4*)(ap + 4);
            bf16x8 a;
            a[0] = (short)f2bf(v0.x); a[1] = (short)f2bf(v0.y);
            a[2] = (short)f2bf(v0.z); a[3] = (short)f2bf(v0.w);
            a[4] = (short)f2bf(v1.x); a[5] = (short)f2bf(v1.y);
            a[6] = (short)f2bf(v1.z); a[7] = (short)f2bf(v1.w);
            afr[r] = a;
        }
#pragma unroll
        for (int c = 0; c < 4; c++) {
            bf16x8 bfr = __builtin_bit_cast(
                bf16x8,
                *(const uint4*)&sWT[(c * 16 + l16) * (K + 8) + chunk * 32 + quad * 8]);
#pragma unroll
            for (int r = 0; r < 2; r++)
                acc[r][c] = __builtin_amdgcn_mfma_f32_16x16x32_bf16(
                    afr[r], bfr, acc[r][c], 0, 0, 0);
        }
    }
#pragma unroll
    for (int r = 0; r < 2; r++)
#pragma unroll
        for (int i = 0; i < 4; i++) {
            int row = rowBase + r * 16 + quad * 4 + i;
            if (row < nrows) {
                float sc = dinv[row];
#pragma unroll
                for (int c = 0; c < 4; c++)
                    out[(size_t)row * 64 + c * 16 + l16] =
                        (ushort_t)f2bf(acc[r][c][i] * sc);
            }
        }
}

// ---- gemm64: (N x 64) @ (64 x 64), bf16 in, dinv-scaled, bf16 out ---------
__global__ __launch_bounds__(256) void k_gemm64(
        const ushort_t* __restrict__ A, const float* __restrict__ W,
        const float* __restrict__ dinv, ushort_t* __restrict__ out, int nrows) {
    const int K = 64;
    __shared__ ushort_t sWT[64 * (K + 8)];
    int tid = threadIdx.x;
    for (int i = tid; i < K * 64; i += 256) {
        int n = i & 63, k = i >> 6;
        sWT[n * (K + 8) + k] = (ushort_t)f2bf(W[i]);
    }
    __syncthreads();
    int wave = tid >> 6, lane = tid & 63;
    int quad = lane >> 4, l16 = lane & 15;
    int rowBase = blockIdx.x * 128 + wave * 32;
    f32x4 acc[2][4];
#pragma unroll
    for (int r = 0; r < 2; r++)
#pragma unroll
        for (int c = 0; c < 4; c++) acc[r][c] = (f32x4){0.f, 0.f, 0.f, 0.f};
#pragma unroll
    for (int chunk = 0; chunk < K / 32; chunk++) {
        bf16x8 afr[2];
#pragma unroll
        for (int r = 0; r < 2; r++) {
            int row = rowBase + r * 16 + l16;
            if (row >= nrows) row = nrows - 1;
            const ushort_t* ap = A + (size_t)row * K + chunk * 32 + quad * 8;
            afr[r] = __builtin_bit_cast(bf16x8, *(const uint4*)ap);
        }
#pragma unroll
        for (int c = 0; c < 4; c++) {
            bf16x8 bfr = __builtin_bit_cast(
                bf16x8,
                *(const uint4*)&sWT[(c * 16 + l16) * (K + 8) + chunk * 32 + quad * 8]);
#pragma unroll
            for (int r = 0; r < 2; r++)
                acc[r][c] = __builtin_amdgcn_mfma_f32_16x16x32_bf16(
                    afr[r], bfr, acc[r][c], 0, 0, 0);
        }
    }
#pragma unroll
    for (int r = 0; r < 2; r++)
#pragma unroll
        for (int i = 0; i < 4; i++) {
            int row = rowBase + r * 16 + quad * 4 + i;
            if (row < nrows) {
                float sc = dinv[row];
#pragma unroll
                for (int c = 0; c < 4; c++)
                    out[(size_t)row * 64 + c * 16 + l16] =
                        (ushort_t)f2bf(acc[r][c][i] * sc);
            }
        }
}

// ---- aggregation: ONE node per wave, 4 features/lane, 4 edges/load --------
// Row = 64 bf16 = 128B = 16 lanes x uint2. Lane group g = lane>>4 handles
// edge slot 4t+g; col[e+4t+g] loaded directly (16-lane broadcast; 4 col loads
// per burst = one 64B line). Col loads software-pipelined depth-2: next
// burst's cols issue before accumulating current gathers, so the per-burst
// chain is gather-wait only (vmcnt(4) leaves cols in flight). Segments padded
// to x4 (sentinel row N = zeros). Tails: 8 then 4 edges, branch-uniform.
// Cross-group reduce via shfl_xor(16/32); lanes 0-15 write the row.
template <int RELU, int F32OUT>
__global__ __launch_bounds__(256) void k_agg4e(
        const ushort_t* __restrict__ hs, const float* __restrict__ dinv,
        const float* __restrict__ bias, const int* __restrict__ col,
        const int2* __restrict__ rp2, const ushort_t* __restrict__ residb,
        float* __restrict__ outf, ushort_t* __restrict__ outb, int n) {
    int node = (int)((blockIdx.x * blockDim.x + threadIdx.x) >> 6);
    if (node >= n) return;
    int lane = threadIdx.x & 63;
    int g = lane >> 4;                   // edge sub-slot within a burst
    int c4 = lane & 15;                  // feature group: cols c4*4..c4*4+3
    const ushort_t* hrow = hs + (size_t)c4 * 4;
    int2 r = rp2[node];
    int e = r.x, p = r.y;                // p-e multiple of 4
    uint2 us = *(const uint2*)(hs + (size_t)node * 64 + c4 * 4);  // self loop
    float a0 = 0.f, a1 = 0.f, a2 = 0.f, a3 = 0.f;

#define GR(m) (*(const uint2*)(hrow + (size_t)(m) * 64))
#define GACC(u)                                                             \
    a0 += bflo(u.x); a1 += bfhi(u.x);                                       \
    a2 += bflo(u.y); a3 += bfhi(u.y);

    int m0, m1, m2, m3;
    bool run = (e + 16 <= p);
    if (run) {
        m0 = col[e + g];      m1 = col[e + 4 + g];
        m2 = col[e + 8 + g];  m3 = col[e + 12 + g];
    }
    while (run) {
        uint2 u0 = GR(m0);
        uint2 u1 = GR(m1);
        uint2 u2 = GR(m2);
        uint2 u3 = GR(m3);
        e += 16;
        run = (e + 16 <= p);
        if (run) {                       // issue next cols BEFORE consuming
            m0 = col[e + g];      m1 = col[e + 4 + g];
            m2 = col[e + 8 + g];  m3 = col[e + 12 + g];
        }
        GACC(u0) GACC(u1) GACC(u2) GACC(u3)
    }
    if (p - e >= 8) {
        int t0 = col[e + g];
        int t1 = col[e + 4 + g];
        uint2 u0 = GR(t0);
        uint2 u1 = GR(t1);
        GACC(u0) GACC(u1)
        e += 8;
    }
    if (e < p) {                         // exactly 4 edges remain
        int t0 = col[e + g];
        uint2 u0 = GR(t0);
        GACC(u0)
    }
#undef GR
#undef GACC

    a0 += __shfl_xor(a0, 16); a0 += __shfl_xor(a0, 32);
    a1 += __shfl_xor(a1, 16); a1 += __shfl_xor(a1, 32);
    a2 += __shfl_xor(a2, 16); a2 += __shfl_xor(a2, 32);
    a3 += __shfl_xor(a3, 16); a3 += __shfl_xor(a3, 32);

    if (lane < 16) {
        a0 += bflo(us.x); a1 += bfhi(us.x);
        a2 += bflo(us.y); a3 += bfhi(us.y);
        float sc = dinv[node];
        float4 bv = *(const float4*)(bias + c4 * 4);
        float o0 = sc * a0 + bv.x, o1 = sc * a1 + bv.y;
        float o2 = sc * a2 + bv.z, o3 = sc * a3 + bv.w;
        if (RELU) {
            o0 = fmaxf(o0, 0.f); o1 = fmaxf(o1, 0.f);
            o2 = fmaxf(o2, 0.f); o3 = fmaxf(o3, 0.f);
        }
        if (F32OUT) {
            uint2 rb = *(const uint2*)(residb + (size_t)node * 64 + c4 * 4);
            o0 += bflo(rb.x); o1 += bfhi(rb.x);
            o2 += bflo(rb.y); o3 += bfhi(rb.y);
            *(float4*)(outf + (size_t)node * 64 + c4 * 4) =
                make_float4(o0, o1, o2, o3);
        } else {
            unsigned w0 = f2bf(o0) | (f2bf(o1) << 16);
            unsigned w1 = f2bf(o2) | (f2bf(o3) << 16);
            *(uint2*)(outb + (size_t)node * 64 + c4 * 4) = make_uint2(w0, w1);
        }
    }
}

// ---------------------------------------------------------------------------
extern "C" void kernel_launch(void* const* d_in, const int* in_sizes, int n_in,
                              void* d_out, int out_size, void* d_ws, size_t ws_size,
                              hipStream_t stream) {
    const float* x  = (const float*)d_in[0];
    const int*   ei = (const int*)d_in[1];
    const float* W0 = (const float*)d_in[2];
    const float* b0 = (const float*)d_in[3];
    const float* Ws = (const float*)d_in[4];
    const float* bs = (const float*)d_in[5];
    float* out = (float*)d_out;

    const int N = in_sizes[0] / 128;
    const int E = in_sizes[1] / 2;
    const int B = (N + BKN - 1) >> LB;

    char* p = (char*)d_ws;
    auto carve = [&](size_t bytes) {
        char* r = p;
        p += (bytes + 255) & ~(size_t)255;
        return r;
    };
    int*      bucketCursor = (int*)carve(512 * 4);
    unsigned* packed       = (unsigned*)carve((size_t)B * CAP * 4);
    int*      col          = (int*)carve(((size_t)B * CAPCOL + 64) * 4);
    int2*     rp2          = (int2*)carve((size_t)N * 8);
    float*    dinv         = (float*)carve((size_t)N * 4);
    ushort_t* hs           = (ushort_t*)carve((size_t)(N + 1) * 64 * 2); // +sentinel
    ushort_t* xtb          = (ushort_t*)carve((size_t)N * 64 * 2);
    ushort_t* hb           = (ushort_t*)carve((size_t)N * 64 * 2);

    hipMemsetAsync(bucketCursor, 0, 512 * 4, stream);

    k_scatter<<<(E + CHUNK - 1) / CHUNK, 256, 0, stream>>>(ei, E, bucketCursor, packed);
    k_sort<<<B, 256, 0, stream>>>(packed, bucketCursor, col, rp2, dinv, hs, N);

    int gb = (N + 127) / 128;
    int ablocks = (N + 3) / 4;   // 1 node/wave, 4 waves/block

    // layer 1: hs = (x @ W0) * dinv ; agg1 -> xtb (bf16, +b0, no relu)
    k_gemm1<<<gb, 256, 0, stream>>>(x, W0, dinv, hs, N);
    k_agg4e<0, 0><<<ablocks, 256, 0, stream>>>(hs, dinv, b0, col, rp2,
                                               nullptr, nullptr, xtb, N);
    // layer 2: hs = (xtb @ Ws0) * dinv ; agg2 -> hb (bf16, +bs0, relu)
    k_gemm64<<<gb, 256, 0, stream>>>(xtb, Ws, dinv, hs, N);
    k_agg4e<1, 0><<<ablocks, 256, 0, stream>>>(hs, dinv, bs, col, rp2,
                                               nullptr, nullptr, hb, N);
    // layer 3: hs = (hb @ Ws1) * dinv ; agg3 -> out (f32, +bs1, relu, +resid)
    k_gemm64<<<gb, 256, 0, stream>>>(hb, Ws + 64 * 64, dinv, hs, N);
    k_agg4e<1, 1><<<ablocks, 256, 0, stream>>>(hs, dinv, bs + 64, col, rp2,
                                               xtb, out, nullptr, N);
}